// Round 16
// baseline (249.323 us; speedup 1.0000x reference)
//
#include <hip/hip_runtime.h>

#define B_     8
#define CIN_   512
#define COUT_  512
#define HW_    64
#define SDIM_  512
#define NPIX   4096      // pixels per image
#define KTOT   4608      // 9*512
#define PADW   66

typedef __attribute__((ext_vector_type(4))) float f32x4;
typedef __attribute__((ext_vector_type(8))) short bf16x8;
typedef __attribute__((ext_vector_type(8))) unsigned short u16x8;

__device__ __forceinline__ float bf2f(unsigned short b) {
    unsigned int u = ((unsigned int)b) << 16;
    return __builtin_bit_cast(float, u);
}
__device__ __forceinline__ unsigned short f2bf(float f) {
    unsigned int u = __builtin_bit_cast(unsigned int, f);
    return (unsigned short)((u + 0x7fffu + ((u >> 16) & 1u)) >> 16);
}
__device__ __forceinline__ float ldin(const void* p, size_t i, int isbf) {
    return isbf ? bf2f(((const unsigned short*)p)[i]) : ((const float*)p)[i];
}

#define GLD16(g, l) __builtin_amdgcn_global_load_lds( \
    (__attribute__((address_space(1))) void*)(g),     \
    (__attribute__((address_space(3))) void*)(l), 16, 0, 0)

// ---------------- dtype detection (unchanged, verified) ----------------
__global__ void detect_dtype(const unsigned int* __restrict__ style_u32,
                             int* __restrict__ flag) {
    int t = threadIdx.x;
    unsigned int w = style_u32[t * 4];
    int e = (w >> 7) & 0xFF;
    int isbf = (e >= 110 && e <= 140) ? 1 : 0;
    __shared__ int cnt;
    if (t == 0) cnt = 0;
    __syncthreads();
    atomicAdd(&cnt, isbf);
    __syncthreads();
    if (t == 0) *flag = (cnt >= 128) ? 1 : 0;
}

// ---------------- zero halo ring of xtp2 [b][cit][66][66][64] ----------------
__global__ void halo_zero(unsigned int* __restrict__ xtp2u) {
    int idx = blockIdx.x;        // 0..259 ring positions
    int b = blockIdx.y;
    int y, x;
    if (idx < 66)       { y = 0;  x = idx; }
    else if (idx < 132) { y = 65; x = idx - 66; }
    else if (idx < 196) { x = 0;  y = idx - 131; }
    else                { x = 65; y = idx - 195; }
    int t = threadIdx.x;          // 256 = 8 cit x 32 u32
    int cit = t >> 5, j = t & 31;
    size_t u32i = ((((size_t)(b * 8 + cit) * 66 + y) * 66 + x) << 5) + j;
    xtp2u[u32i] = 0;
}

// ---------------- kernel (k,co) -> Wt (co,k) transpose (unchanged) ----------------
__global__ void wt_transpose(const void* __restrict__ kin,
                             unsigned short* __restrict__ wt,
                             const int* __restrict__ flag) {
    __shared__ __align__(16) unsigned short tile[64][72];
    int isbf = *flag;
    int t = threadIdx.x;
    int co0 = blockIdx.x * 64;
    int k0  = blockIdx.y * 64;
    int r = t >> 2, c16 = (t & 3) << 4;
    if (isbf) {
        const unsigned short* src = (const unsigned short*)kin + (size_t)(k0 + r) * COUT_ + co0 + c16;
        *(u16x8*)&tile[r][c16]     = *(const u16x8*)src;
        *(u16x8*)&tile[r][c16 + 8] = *(const u16x8*)(src + 8);
    } else {
        const float* src = (const float*)kin + (size_t)(k0 + r) * COUT_ + co0 + c16;
#pragma unroll
        for (int q = 0; q < 4; ++q) {
            f32x4 v = *(const f32x4*)(src + q * 4);
#pragma unroll
            for (int j = 0; j < 4; ++j) tile[r][c16 + q * 4 + j] = f2bf(v[j]);
        }
    }
    __syncthreads();
    int c = t >> 2, r16 = (t & 3) << 4;
    u16x8 w0, w1;
#pragma unroll
    for (int j = 0; j < 8; ++j) { w0[j] = tile[r16 + j][c]; w1[j] = tile[r16 + 8 + j][c]; }
    unsigned short* dst = wt + (size_t)(co0 + c) * KTOT + k0 + r16;
    *(u16x8*)dst       = w0;
    *(u16x8*)(dst + 8) = w1;
}

// ---------------- x NCHW -> padded bf16 ci-tile-major [b][cit][66][66][64] ----------------
__global__ void xpose(const void* __restrict__ x,
                      unsigned short* __restrict__ xtp2,
                      const int* __restrict__ flag) {
    __shared__ __align__(16) unsigned short tile[64][72];
    int isbf = *flag;
    int t = threadIdx.x;
    int cit = blockIdx.x;
    int y   = blockIdx.y;
    int b   = blockIdx.z;
    int ci_l = t >> 2, xo = (t & 3) << 4;
    size_t srcoff = (((size_t)(b * CIN_ + cit * 64 + ci_l)) * HW_ + y) * HW_ + xo;
    if (isbf) {
        const unsigned short* src = (const unsigned short*)x + srcoff;
        *(u16x8*)&tile[ci_l][xo]     = *(const u16x8*)src;
        *(u16x8*)&tile[ci_l][xo + 8] = *(const u16x8*)(src + 8);
    } else {
        const float* src = (const float*)x + srcoff;
#pragma unroll
        for (int q = 0; q < 4; ++q) {
            f32x4 v = *(const f32x4*)(src + q * 4);
#pragma unroll
            for (int j = 0; j < 4; ++j) tile[ci_l][xo + q * 4 + j] = f2bf(v[j]);
        }
    }
    __syncthreads();
    int xl = t >> 2, cio = (t & 3) << 4;
    u16x8 w0, w1;
#pragma unroll
    for (int j = 0; j < 8; ++j) { w0[j] = tile[cio + j][xl]; w1[j] = tile[cio + 8 + j][xl]; }
    unsigned short* dst =
        xtp2 + ((((size_t)(b * 8 + cit) * 66 + (y + 1)) * 66 + (xl + 1)) << 6) + cio;
    *(u16x8*)dst       = w0;
    *(u16x8*)(dst + 8) = w1;
}

// ---------------- mod scale (unchanged) ----------------
__global__ void mod_kernel(const void* __restrict__ style,
                           const void* __restrict__ sscale,
                           const unsigned short* __restrict__ wt,
                           float* __restrict__ mmod,
                           const int* __restrict__ flag) {
    int isbf = *flag;
    int co = blockIdx.x, t = threadIdx.x;
    int lane = t & 63, wid = t >> 6;
    float k2 = 0.f;
    const unsigned short* wr = wt + (size_t)co * KTOT;
    for (int k = t; k < KTOT; k += 256) { float v = bf2f(wr[k]); k2 += v * v; }
    float sb[B_];
#pragma unroll
    for (int b = 0; b < B_; ++b) sb[b] = 0.f;
    for (int sd = t; sd < SDIM_; sd += 256) {
        float ss = ldin(sscale, (size_t)sd * COUT_ + co, isbf);
#pragma unroll
        for (int b = 0; b < B_; ++b) sb[b] += ldin(style, b * SDIM_ + sd, isbf) * ss;
    }
    __shared__ float red[4][9];
    float vals[9];
    vals[0] = k2;
#pragma unroll
    for (int b = 0; b < B_; ++b) vals[1 + b] = sb[b];
#pragma unroll
    for (int q = 0; q < 9; ++q) {
        float v = vals[q];
        for (int off = 32; off; off >>= 1) v += __shfl_down(v, off);
        if (lane == 0) red[wid][q] = v;
    }
    __syncthreads();
    if (t < B_) {
        int b = t;
        float k2t = red[0][0] + red[1][0] + red[2][0] + red[3][0];
        float s   = red[0][1 + b] + red[1][1 + b] + red[2][1 + b] + red[3][1 + b];
        float sp1 = s + 1.f;
        mmod[b * COUT_ + co] = sp1 * rsqrtf(sp1 * sp1 * k2t + 1e-8f);
    }
}

// ---------------- implicit-GEMM conv: window B + register kk-pipeline ----------------
// Every MFMA cluster consumes the PREVIOUS kk-step's fragments (register-held),
// while the next set's 12 ds_reads issue underneath:
//   tile t: stage A(t+1); read R(kk0); MFMA H(=kk1 of t-1); read->H(kk1); MFMA R;
//           lgkm(0); vmcnt(0); barrier.
// Breaks the within-wave read->MFMA serialization (the 40% MfmaUtil invariant
// across 12 schedule/occupancy/shape variants). ~250 VGPR (acc128 + 2x48 frags).
__global__ __launch_bounds__(512, 2) void conv_gemm(
    const unsigned short* __restrict__ wt,
    const unsigned short* __restrict__ xtp2,
    const float* __restrict__ mmod,
    const void* __restrict__ noise,
    const void* __restrict__ bias,
    const void* __restrict__ nwp,
    void* __restrict__ out,
    const int* __restrict__ flag) {
    __shared__ __align__(1024) unsigned short Asm[2][256 * 64];   // 64 KiB
    __shared__ __align__(1024) unsigned short Win[6 * 72 * 64];   // 55.3 KiB
    int isbf = *flag;
    int tid = threadIdx.x;
    int lane = tid & 63, wid = tid >> 6;
    int lr = lane & 15, hi = lane >> 4;
    int wm = wid >> 2, wn = wid & 3;          // 2 x 4 wave grid; wave = 128co x 64px(row wn)

    int bid = blockIdx.x;
    int swz = (bid & 7) * 32 + (bid >> 3);    // XCD-chunked bijective (256 % 8 == 0)
    int gy = swz >> 7;
    int nb = swz & 127;
    int b  = nb >> 4;
    int nt = nb & 15;
    int pl0 = nt << 8;                        // 256 pixels = 4 image rows
    int h0  = pl0 >> 6;
    int co0 = gy << 8;

    f32x4 acc[8][4];
#pragma unroll
    for (int i = 0; i < 8; ++i)
#pragma unroll
        for (int j = 0; j < 4; ++j) acc[i][j] = (f32x4){0.f, 0.f, 0.f, 0.f};

    int rsub = lane >> 3;
    int ce_src = ((lane & 7) ^ rsub) << 3;    // A pre-swizzled source column (elems)
    int swzr = (lane & 7) << 3;               // A read XOR
    int wsrc = (rsub << 6) + (((lane & 7) ^ (rsub & 7)) << 3);  // window stage src (elems)
    int l7 = lane & 7;
    int px[4];                                 // per-ni pixel-column bases (elems)
#pragma unroll
    for (int ni = 0; ni < 4; ++ni) px[ni] = ((ni << 4) + lr) << 6;

    auto stageA = [&](int koff, int pp, int q) {
        const unsigned short* srcA =
            wt + (size_t)(co0 + (q << 6) + (wid << 3) + rsub) * KTOT + koff + ce_src;
        GLD16(srcA, (char*)&Asm[pp][0] + (q << 13) + (wid << 10));
    };
    auto stage_win = [&](int cit) {
        size_t base = ((size_t)(b * 8 + cit) * 66 + h0) * (66 * 64);
        for (int idx = wid; idx < 54; idx += 8) {       // 6 rows x 9 chunks
            int r = idx / 9, g = idx - r * 9;
            const unsigned short* src = xtp2 + base + (size_t)r * (66 * 64) + (g << 9) + wsrc;
            GLD16(src, (char*)Win + r * 9216 + (g << 10));
        }
    };

    bf16x8 Ha[8], Hb[4];   // held set (kk1 of previous tile)
    bf16x8 Ra[8], Rb[4];   // current kk0 set

    // prologue: window(cit=0) + A(tile 0)
    stage_win(0);
#pragma unroll
    for (int q = 0; q < 4; ++q) stageA(0, 0, q);
    asm volatile("s_waitcnt vmcnt(0)" ::: "memory");
    __builtin_amdgcn_s_barrier();
    asm volatile("" ::: "memory");

    int t = 0;
    for (int cit = 0; cit < 8; ++cit) {
        if (cit > 0) {
            stage_win(cit);                    // window readers retired at prev boundary
        }
        for (int khw = 0; khw < 9; ++khw, ++t) {
            int p = t & 1, pn = p ^ 1;
            const unsigned short* As = &Asm[p][0];
            int kh = (khw >= 6) ? 2 : ((khw >= 3) ? 1 : 0);
            int kw = khw - kh * 3;
            int BD = (((wn + kh) * 72) + kw) << 6;         // window base (uniform/wave)
            int xv = ((l7 + kw) & 7) << 3;                 // B read XOR (per-lane)

            // stage A(t+1) -> pn (its readers retired one fence+barrier ago)
            if (t < 71) {
                int khw1 = (khw == 8) ? 0 : khw + 1;
                int cit1 = (khw == 8) ? cit + 1 : cit;
                int koff1 = khw1 * 512 + (cit1 << 6);
#pragma unroll
                for (int q = 0; q < 4; ++q) stageA(koff1, pn, q);
            }

            int kc0 = (hi << 3), kc1 = 32 + (hi << 3);

            // read R = kk0 set (12 b128)
#pragma unroll
            for (int i = 0; i < 8; ++i)
                Ra[i] = *(const bf16x8*)&As[(((wm << 7) + (i << 4) + lr) << 6) + (kc0 ^ swzr)];
#pragma unroll
            for (int ni = 0; ni < 4; ++ni)
                Rb[ni] = *(const bf16x8*)&Win[BD + px[ni] + (kc0 ^ xv)];

            // MFMA on held set H (kk1 of previous tile) -- data already in regs
            if (t > 0) {
                __builtin_amdgcn_s_setprio(1);
#pragma unroll
                for (int mf = 0; mf < 8; ++mf)
#pragma unroll
                    for (int nf = 0; nf < 4; ++nf)
                        acc[mf][nf] = __builtin_amdgcn_mfma_f32_16x16x32_bf16(Ha[mf], Hb[nf], acc[mf][nf], 0, 0, 0);
                __builtin_amdgcn_s_setprio(0);
            }

            // read kk1 set directly into H (WAR on regs orders this after the H MFMAs)
#pragma unroll
            for (int i = 0; i < 8; ++i)
                Ha[i] = *(const bf16x8*)&As[(((wm << 7) + (i << 4) + lr) << 6) + (kc1 ^ swzr)];
#pragma unroll
            for (int ni = 0; ni < 4; ++ni)
                Hb[ni] = *(const bf16x8*)&Win[BD + px[ni] + (kc1 ^ xv)];

            // MFMA on R (kk0); H-set reads (12) drain underneath
            __builtin_amdgcn_s_setprio(1);
#pragma unroll
            for (int mf = 0; mf < 8; ++mf)
#pragma unroll
                for (int nf = 0; nf < 4; ++nf)
                    acc[mf][nf] = __builtin_amdgcn_mfma_f32_16x16x32_bf16(Ra[mf], Rb[nf], acc[mf][nf], 0, 0, 0);
            __builtin_amdgcn_s_setprio(0);

            // ---- tile boundary ----
            asm volatile("s_waitcnt lgkmcnt(0)" ::: "memory");   // H reads retired (drained under MFMA)
            if (t < 71) asm volatile("s_waitcnt vmcnt(0)" ::: "memory");  // A(t+1)+win landed
            __builtin_amdgcn_s_barrier();
            asm volatile("" ::: "memory");
        }
    }

    // flush final held set (kk1 of tile 71)
    __builtin_amdgcn_s_setprio(1);
#pragma unroll
    for (int mf = 0; mf < 8; ++mf)
#pragma unroll
        for (int nf = 0; nf < 4; ++nf)
            acc[mf][nf] = __builtin_amdgcn_mfma_f32_16x16x32_bf16(Ha[mf], Hb[nf], acc[mf][nf], 0, 0, 0);
    __builtin_amdgcn_s_setprio(0);

    // fused epilogue: out = leaky(m*y + nw*noise + bias) * sqrt(2), NCHW
    float nw = ldin(nwp, 0, isbf);
    unsigned short* out16 = (unsigned short*)out;
    float* outf = (float*)out;
#pragma unroll
    for (int mf = 0; mf < 8; ++mf) {
        int cobase = co0 + (wm << 7) + (mf << 4) + (hi << 2);
        f32x4 mv = *(const f32x4*)&mmod[b * COUT_ + cobase];
        float bb[4];
#pragma unroll
        for (int r = 0; r < 4; ++r) bb[r] = ldin(bias, cobase + r, isbf);
#pragma unroll
        for (int nf = 0; nf < 4; ++nf) {
            int pix = pl0 + (wn << 6) + (nf << 4) + lr;
            float nv = nw * ldin(noise, b * NPIX + pix, isbf);
#pragma unroll
            for (int r = 0; r < 4; ++r) {
                float v = acc[mf][nf][r] * mv[r] + nv + bb[r];
                v = (v < 0.f ? v * 0.2f : v) * 1.41421356237f;
                size_t oidx = ((size_t)(b * COUT_ + cobase + r)) * NPIX + pix;
                if (isbf) out16[oidx] = f2bf(v);
                else      outf[oidx]  = v;
            }
        }
    }
}

extern "C" void kernel_launch(void* const* d_in, const int* in_sizes, int n_in,
                              void* d_out, int out_size, void* d_ws, size_t ws_size,
                              hipStream_t stream) {
    const void* x      = d_in[0];
    const void* style  = d_in[1];
    const void* noise  = d_in[2];
    const void* kin    = d_in[3];
    const void* sscale = d_in[4];
    const void* bias   = d_in[5];
    const void* nwp    = d_in[6];

    char* ws = (char*)d_ws;
    int* flag = (int*)ws;
    const size_t xtp_off   = 256;
    const size_t xtp_bytes = (size_t)B_ * 8 * 66 * 66 * 64 * 2;   // 35,684,352 (ci-tile-major)
    const size_t pad       = 4096;                                 // stage_win overrun pad
    const size_t wt_bytes  = (size_t)COUT_ * KTOT * 2;
    unsigned short* xtp2 = (unsigned short*)(ws + xtp_off);
    unsigned short* wtr  = (unsigned short*)(ws + xtp_off + xtp_bytes + pad);
    float* mmod          = (float*)(ws + xtp_off + xtp_bytes + pad + wt_bytes);

    detect_dtype<<<1, 256, 0, stream>>>((const unsigned int*)style, flag);
    halo_zero<<<dim3(260, 8), 256, 0, stream>>>((unsigned int*)xtp2);
    wt_transpose<<<dim3(8, 72), 256, 0, stream>>>(kin, wtr, flag);
    xpose<<<dim3(8, 64, 8), 256, 0, stream>>>(x, xtp2, flag);
    mod_kernel<<<512, 256, 0, stream>>>(style, sscale, wtr, mmod, flag);
    conv_gemm<<<256, 512, 0, stream>>>(wtr, xtp2, mmod, noise, bias, nwp, d_out, flag);
}

// Round 17
// 179.593 us; speedup vs baseline: 1.3883x; 1.3883x over previous
//
#include <hip/hip_runtime.h>

#define B_     8
#define CIN_   512
#define COUT_  512
#define HW_    64
#define SDIM_  512
#define NPIX   4096      // pixels per image
#define KTOT   4608      // 9*512
#define PADW   66

typedef __attribute__((ext_vector_type(4))) float f32x4;
typedef __attribute__((ext_vector_type(8))) short bf16x8;
typedef __attribute__((ext_vector_type(8))) unsigned short u16x8;

__device__ __forceinline__ float bf2f(unsigned short b) {
    unsigned int u = ((unsigned int)b) << 16;
    return __builtin_bit_cast(float, u);
}
__device__ __forceinline__ unsigned short f2bf(float f) {
    unsigned int u = __builtin_bit_cast(unsigned int, f);
    return (unsigned short)((u + 0x7fffu + ((u >> 16) & 1u)) >> 16);
}
__device__ __forceinline__ float ldin(const void* p, size_t i, int isbf) {
    return isbf ? bf2f(((const unsigned short*)p)[i]) : ((const float*)p)[i];
}

#define GLD16(g, l) __builtin_amdgcn_global_load_lds( \
    (__attribute__((address_space(1))) void*)(g),     \
    (__attribute__((address_space(3))) void*)(l), 16, 0, 0)

// ---------------- dtype detection (unchanged, verified) ----------------
__global__ void detect_dtype(const unsigned int* __restrict__ style_u32,
                             int* __restrict__ flag) {
    int t = threadIdx.x;
    unsigned int w = style_u32[t * 4];
    int e = (w >> 7) & 0xFF;
    int isbf = (e >= 110 && e <= 140) ? 1 : 0;
    __shared__ int cnt;
    if (t == 0) cnt = 0;
    __syncthreads();
    atomicAdd(&cnt, isbf);
    __syncthreads();
    if (t == 0) *flag = (cnt >= 128) ? 1 : 0;
}

// ---------------- kernel (k,co) -> Wt (co,k) transpose (unchanged) ----------------
__global__ void wt_transpose(const void* __restrict__ kin,
                             unsigned short* __restrict__ wt,
                             const int* __restrict__ flag) {
    __shared__ __align__(16) unsigned short tile[64][72];
    int isbf = *flag;
    int t = threadIdx.x;
    int co0 = blockIdx.x * 64;
    int k0  = blockIdx.y * 64;
    int r = t >> 2, c16 = (t & 3) << 4;
    if (isbf) {
        const unsigned short* src = (const unsigned short*)kin + (size_t)(k0 + r) * COUT_ + co0 + c16;
        *(u16x8*)&tile[r][c16]     = *(const u16x8*)src;
        *(u16x8*)&tile[r][c16 + 8] = *(const u16x8*)(src + 8);
    } else {
        const float* src = (const float*)kin + (size_t)(k0 + r) * COUT_ + co0 + c16;
#pragma unroll
        for (int q = 0; q < 4; ++q) {
            f32x4 v = *(const f32x4*)(src + q * 4);
#pragma unroll
            for (int j = 0; j < 4; ++j) tile[r][c16 + q * 4 + j] = f2bf(v[j]);
        }
    }
    __syncthreads();
    int c = t >> 2, r16 = (t & 3) << 4;
    u16x8 w0, w1;
#pragma unroll
    for (int j = 0; j < 8; ++j) { w0[j] = tile[r16 + j][c]; w1[j] = tile[r16 + 8 + j][c]; }
    unsigned short* dst = wt + (size_t)(co0 + c) * KTOT + k0 + r16;
    *(u16x8*)dst       = w0;
    *(u16x8*)(dst + 8) = w1;
}

// ---------------- x NCHW -> padded bf16 ci-tile-major [b][cit][66][66][64] ----------------
// Halo fused: blockIdx.y = dst padded row 0..65. Rows 0/65 write zeros; interior
// rows transpose src row yy-1 and zero their own edge cells (x=0, x=65).
__global__ void xpose(const void* __restrict__ x,
                      unsigned short* __restrict__ xtp2,
                      const int* __restrict__ flag) {
    __shared__ __align__(16) unsigned short tile[64][72];
    int t = threadIdx.x;
    int cit = blockIdx.x;
    int yy  = blockIdx.y;    // dst padded row
    int b   = blockIdx.z;
    size_t rowbase = (((size_t)(b * 8 + cit) * 66 + yy) * 66) << 6;   // elems
    if (yy == 0 || yy == 65) {
        unsigned int* dst = (unsigned int*)(xtp2 + rowbase);
        for (int i = t; i < 66 * 32; i += 256) dst[i] = 0;   // 66 cells x 64 ci
        return;
    }
    int isbf = *flag;
    int y = yy - 1;
    int ci_l = t >> 2, xo = (t & 3) << 4;
    size_t srcoff = (((size_t)(b * CIN_ + cit * 64 + ci_l)) * HW_ + y) * HW_ + xo;
    if (isbf) {
        const unsigned short* src = (const unsigned short*)x + srcoff;
        *(u16x8*)&tile[ci_l][xo]     = *(const u16x8*)src;
        *(u16x8*)&tile[ci_l][xo + 8] = *(const u16x8*)(src + 8);
    } else {
        const float* src = (const float*)x + srcoff;
#pragma unroll
        for (int q = 0; q < 4; ++q) {
            f32x4 v = *(const f32x4*)(src + q * 4);
#pragma unroll
            for (int j = 0; j < 4; ++j) tile[ci_l][xo + q * 4 + j] = f2bf(v[j]);
        }
    }
    // zero this row's halo cells x=0 and x=65 (64 ci each = 32 u32)
    if (t < 64) {
        unsigned int* d0 = (unsigned int*)(xtp2 + rowbase);               // x=0
        unsigned int* d1 = (unsigned int*)(xtp2 + rowbase + (65 << 6));   // x=65
        if (t < 32) d0[t] = 0; else d1[t - 32] = 0;
    }
    __syncthreads();
    int xl = t >> 2, cio = (t & 3) << 4;
    u16x8 w0, w1;
#pragma unroll
    for (int j = 0; j < 8; ++j) { w0[j] = tile[cio + j][xl]; w1[j] = tile[cio + 8 + j][xl]; }
    unsigned short* dst = xtp2 + rowbase + ((size_t)(xl + 1) << 6) + cio;
    *(u16x8*)dst       = w0;
    *(u16x8*)(dst + 8) = w1;
}

// ---------------- mod scale (unchanged) ----------------
__global__ void mod_kernel(const void* __restrict__ style,
                           const void* __restrict__ sscale,
                           const unsigned short* __restrict__ wt,
                           float* __restrict__ mmod,
                           const int* __restrict__ flag) {
    int isbf = *flag;
    int co = blockIdx.x, t = threadIdx.x;
    int lane = t & 63, wid = t >> 6;
    float k2 = 0.f;
    const unsigned short* wr = wt + (size_t)co * KTOT;
    for (int k = t; k < KTOT; k += 256) { float v = bf2f(wr[k]); k2 += v * v; }
    float sb[B_];
#pragma unroll
    for (int b = 0; b < B_; ++b) sb[b] = 0.f;
    for (int sd = t; sd < SDIM_; sd += 256) {
        float ss = ldin(sscale, (size_t)sd * COUT_ + co, isbf);
#pragma unroll
        for (int b = 0; b < B_; ++b) sb[b] += ldin(style, b * SDIM_ + sd, isbf) * ss;
    }
    __shared__ float red[4][9];
    float vals[9];
    vals[0] = k2;
#pragma unroll
    for (int b = 0; b < B_; ++b) vals[1 + b] = sb[b];
#pragma unroll
    for (int q = 0; q < 9; ++q) {
        float v = vals[q];
        for (int off = 32; off; off >>= 1) v += __shfl_down(v, off);
        if (lane == 0) red[wid][q] = v;
    }
    __syncthreads();
    if (t < B_) {
        int b = t;
        float k2t = red[0][0] + red[1][0] + red[2][0] + red[3][0];
        float s   = red[0][1 + b] + red[1][1 + b] + red[2][1 + b] + red[3][1 + b];
        float sp1 = s + 1.f;
        mmod[b * COUT_ + co] = sp1 * rsqrtf(sp1 * sp1 * k2t + 1e-8f);
    }
}

// ---------------- implicit-GEMM conv: ci-outer, B-window, SGB read/MFMA interleave ----------------
// R13 best-verified configuration (conv 163.4us, 948 TF, MfmaUtil 40%, FETCH 45MB,
// 0 bank conflicts). 13 variants across schedule/occupancy/shape/memory-path axes
// all pin at ~40% MfmaUtil — the plain-HIP structural plateau for this conv.
__global__ __launch_bounds__(512, 2) void conv_gemm(
    const unsigned short* __restrict__ wt,
    const unsigned short* __restrict__ xtp2,
    const float* __restrict__ mmod,
    const void* __restrict__ noise,
    const void* __restrict__ bias,
    const void* __restrict__ nwp,
    void* __restrict__ out,
    const int* __restrict__ flag) {
    __shared__ __align__(1024) unsigned short Asm[2][256 * 64];   // 64 KiB
    __shared__ __align__(1024) unsigned short Win[6 * 72 * 64];   // 55.3 KiB
    int isbf = *flag;
    int tid = threadIdx.x;
    int lane = tid & 63, wid = tid >> 6;
    int lr = lane & 15, hi = lane >> 4;
    int wm = wid >> 2, wn = wid & 3;          // 2 x 4 wave grid; wave = 128co x 64px(row wn)

    int bid = blockIdx.x;
    int swz = (bid & 7) * 32 + (bid >> 3);    // XCD-chunked bijective (256 % 8 == 0)
    int gy = swz >> 7;
    int nb = swz & 127;
    int b  = nb >> 4;
    int nt = nb & 15;
    int pl0 = nt << 8;                        // 256 pixels = 4 image rows
    int h0  = pl0 >> 6;
    int co0 = gy << 8;

    f32x4 acc[8][4];
#pragma unroll
    for (int i = 0; i < 8; ++i)
#pragma unroll
        for (int j = 0; j < 4; ++j) acc[i][j] = (f32x4){0.f, 0.f, 0.f, 0.f};

    int rsub = lane >> 3;
    int ce_src = ((lane & 7) ^ rsub) << 3;    // A pre-swizzled source column (elems)
    int swzr = (lane & 7) << 3;               // A read XOR
    int wsrc = (rsub << 6) + (((lane & 7) ^ (rsub & 7)) << 3);  // window stage src (elems)
    int l7 = lane & 7;
    int px[4];                                 // per-ni pixel-column bases (elems)
#pragma unroll
    for (int ni = 0; ni < 4; ++ni) px[ni] = ((ni << 4) + lr) << 6;

    auto stageA = [&](int koff, int pp, int q) {
        const unsigned short* srcA =
            wt + (size_t)(co0 + (q << 6) + (wid << 3) + rsub) * KTOT + koff + ce_src;
        GLD16(srcA, (char*)&Asm[pp][0] + (q << 13) + (wid << 10));
    };
    auto stage_win = [&](int cit) {
        size_t base = ((size_t)(b * 8 + cit) * 66 + h0) * (66 * 64);
        for (int idx = wid; idx < 54; idx += 8) {       // 6 rows x 9 chunks
            int r = idx / 9, g = idx - r * 9;
            const unsigned short* src = xtp2 + base + (size_t)r * (66 * 64) + (g << 9) + wsrc;
            GLD16(src, (char*)Win + r * 9216 + (g << 10));
        }
    };

    // prologue: window(cit=0) + A(tile 0, koff=0)
    stage_win(0);
#pragma unroll
    for (int q = 0; q < 4; ++q) stageA(0, 0, q);
    asm volatile("s_waitcnt vmcnt(0)" ::: "memory");
    __builtin_amdgcn_s_barrier();
    asm volatile("" ::: "memory");

    int t = 0;
    for (int cit = 0; cit < 8; ++cit) {
        if (cit > 0) {
            stage_win(cit);                    // window readers retired at prev tile end
            asm volatile("s_waitcnt vmcnt(0)" ::: "memory");
            __builtin_amdgcn_s_barrier();
            asm volatile("" ::: "memory");
        }
        for (int khw = 0; khw < 9; ++khw, ++t) {
            int p = t & 1, pn = p ^ 1;
            const unsigned short* As = &Asm[p][0];
            int kh = (khw >= 6) ? 2 : ((khw >= 3) ? 1 : 0);
            int kw = khw - kh * 3;
            int BD = (((wn + kh) * 72) + kw) << 6;         // window base (uniform/wave)
            int xv = ((l7 + kw) & 7) << 3;                 // B read XOR (per-lane)

            // stage A(t+1) -> pn (its readers retired one fence+barrier ago)
            if (t < 71) {
                int khw1 = (khw == 8) ? 0 : khw + 1;
                int cit1 = (khw == 8) ? cit + 1 : cit;
                int koff1 = khw1 * 512 + (cit1 << 6);
#pragma unroll
                for (int q = 0; q < 4; ++q) stageA(koff1, pn, q);
            }

            int kc0 = (hi << 3), kc1 = 32 + (hi << 3);
            // reads (source order; SGB template below interleaves them into MFMA clusters)
            bf16x8 a0[4], bk0[4], a1[4], a2[4], bk1[4], a3[4];
#pragma unroll
            for (int i = 0; i < 4; ++i)
                a0[i] = *(const bf16x8*)&As[(((wm << 7) + (i << 4) + lr) << 6) + (kc0 ^ swzr)];
#pragma unroll
            for (int ni = 0; ni < 4; ++ni)
                bk0[ni] = *(const bf16x8*)&Win[BD + px[ni] + (kc0 ^ xv)];
#pragma unroll
            for (int i = 0; i < 4; ++i)
                a1[i] = *(const bf16x8*)&As[(((wm << 7) + ((i + 4) << 4) + lr) << 6) + (kc0 ^ swzr)];
#pragma unroll
            for (int i = 0; i < 4; ++i)
                a2[i] = *(const bf16x8*)&As[(((wm << 7) + (i << 4) + lr) << 6) + (kc1 ^ swzr)];
#pragma unroll
            for (int ni = 0; ni < 4; ++ni)
                bk1[ni] = *(const bf16x8*)&Win[BD + px[ni] + (kc1 ^ xv)];
#pragma unroll
            for (int i = 0; i < 4; ++i)
                a3[i] = *(const bf16x8*)&As[(((wm << 7) + ((i + 4) << 4) + lr) << 6) + (kc1 ^ swzr)];

            // MFMA clusters
#pragma unroll
            for (int mf = 0; mf < 4; ++mf)
#pragma unroll
                for (int nf = 0; nf < 4; ++nf)
                    acc[mf][nf] = __builtin_amdgcn_mfma_f32_16x16x32_bf16(a0[mf], bk0[nf], acc[mf][nf], 0, 0, 0);
#pragma unroll
            for (int mf = 0; mf < 4; ++mf)
#pragma unroll
                for (int nf = 0; nf < 4; ++nf)
                    acc[mf + 4][nf] = __builtin_amdgcn_mfma_f32_16x16x32_bf16(a1[mf], bk0[nf], acc[mf + 4][nf], 0, 0, 0);
#pragma unroll
            for (int mf = 0; mf < 4; ++mf)
#pragma unroll
                for (int nf = 0; nf < 4; ++nf)
                    acc[mf][nf] = __builtin_amdgcn_mfma_f32_16x16x32_bf16(a2[mf], bk1[nf], acc[mf][nf], 0, 0, 0);
#pragma unroll
            for (int mf = 0; mf < 4; ++mf)
#pragma unroll
                for (int nf = 0; nf < 4; ++nf)
                    acc[mf + 4][nf] = __builtin_amdgcn_mfma_f32_16x16x32_bf16(a3[mf], bk1[nf], acc[mf + 4][nf], 0, 0, 0);

            // ---- SGB schedule template for this region ----
            __builtin_amdgcn_sched_group_barrier(0x010, 4, 0);   // stage VMEM
            __builtin_amdgcn_sched_group_barrier(0x100, 8, 0);   // a0+bk0
#pragma unroll
            for (int r = 0; r < 4; ++r) {                        // Q0 || a1
                __builtin_amdgcn_sched_group_barrier(0x100, 1, 0);
                __builtin_amdgcn_sched_group_barrier(0x008, 4, 0);
            }
#pragma unroll
            for (int r = 0; r < 8; ++r) {                        // Q1 || a2,bk1
                __builtin_amdgcn_sched_group_barrier(0x100, 1, 0);
                __builtin_amdgcn_sched_group_barrier(0x008, 2, 0);
            }
#pragma unroll
            for (int r = 0; r < 4; ++r) {                        // Q2 || a3
                __builtin_amdgcn_sched_group_barrier(0x100, 1, 0);
                __builtin_amdgcn_sched_group_barrier(0x008, 4, 0);
            }
            __builtin_amdgcn_sched_group_barrier(0x008, 16, 0);  // Q3

            // ---- tile boundary ----
            asm volatile("s_waitcnt lgkmcnt(0)" ::: "memory");   // my LDS reads retired
            if (t < 71) asm volatile("s_waitcnt vmcnt(0)" ::: "memory");  // A(t+1) landed
            __builtin_amdgcn_s_barrier();
            asm volatile("" ::: "memory");
        }
    }

    // fused epilogue: out = leaky(m*y + nw*noise + bias) * sqrt(2), NCHW
    float nw = ldin(nwp, 0, isbf);
    unsigned short* out16 = (unsigned short*)out;
    float* outf = (float*)out;
#pragma unroll
    for (int mf = 0; mf < 8; ++mf) {
        int cobase = co0 + (wm << 7) + (mf << 4) + (hi << 2);
        f32x4 mv = *(const f32x4*)&mmod[b * COUT_ + cobase];
        float bb[4];
#pragma unroll
        for (int r = 0; r < 4; ++r) bb[r] = ldin(bias, cobase + r, isbf);
#pragma unroll
        for (int nf = 0; nf < 4; ++nf) {
            int pix = pl0 + (wn << 6) + (nf << 4) + lr;
            float nv = nw * ldin(noise, b * NPIX + pix, isbf);
#pragma unroll
            for (int r = 0; r < 4; ++r) {
                float v = acc[mf][nf][r] * mv[r] + nv + bb[r];
                v = (v < 0.f ? v * 0.2f : v) * 1.41421356237f;
                size_t oidx = ((size_t)(b * COUT_ + cobase + r)) * NPIX + pix;
                if (isbf) out16[oidx] = f2bf(v);
                else      outf[oidx]  = v;
            }
        }
    }
}

extern "C" void kernel_launch(void* const* d_in, const int* in_sizes, int n_in,
                              void* d_out, int out_size, void* d_ws, size_t ws_size,
                              hipStream_t stream) {
    const void* x      = d_in[0];
    const void* style  = d_in[1];
    const void* noise  = d_in[2];
    const void* kin    = d_in[3];
    const void* sscale = d_in[4];
    const void* bias   = d_in[5];
    const void* nwp    = d_in[6];

    char* ws = (char*)d_ws;
    int* flag = (int*)ws;
    const size_t xtp_off   = 256;
    const size_t xtp_bytes = (size_t)B_ * 8 * 66 * 66 * 64 * 2;   // 35,684,352 (ci-tile-major)
    const size_t pad       = 4096;                                 // stage_win overrun pad
    const size_t wt_bytes  = (size_t)COUT_ * KTOT * 2;
    unsigned short* xtp2 = (unsigned short*)(ws + xtp_off);
    unsigned short* wtr  = (unsigned short*)(ws + xtp_off + xtp_bytes + pad);
    float* mmod          = (float*)(ws + xtp_off + xtp_bytes + pad + wt_bytes);

    detect_dtype<<<1, 256, 0, stream>>>((const unsigned int*)style, flag);
    wt_transpose<<<dim3(8, 72), 256, 0, stream>>>(kin, wtr, flag);
    xpose<<<dim3(8, 66, 8), 256, 0, stream>>>(x, xtp2, flag);     // halo fused
    mod_kernel<<<512, 256, 0, stream>>>(style, sscale, wtr, mmod, flag);
    conv_gemm<<<256, 512, 0, stream>>>(wtr, xtp2, mmod, noise, bias, nwp, d_out, flag);
}